// Round 27
// baseline (172.317 us; speedup 1.0000x reference)
//
#include <hip/hip_runtime.h>
#include <hip/hip_bf16.h>
#include <hip/hip_fp16.h>

#define S_LEN  2048
#define BATCH  2
#define DMODEL 1024
#define NHEADS 16
#define HD     64
#define MROWS  4096   // S*B
#define LD     72     // attn P LDS stride (padded, per-wave)
#define NT     (S_LEN / 64)

using f16 = _Float16;
typedef __attribute__((ext_vector_type(8))) _Float16 f16x8;
typedef __attribute__((ext_vector_type(4))) _Float16 f16x4;
typedef __attribute__((ext_vector_type(4))) float    f32x4;

// async global->LDS, 16B per lane; LDS dest = wave-uniform base + lane*16
__device__ __forceinline__ void gload16(const void* g, void* l)
{
    __builtin_amdgcn_global_load_lds((const __attribute__((address_space(1))) void*)g,
                                     (__attribute__((address_space(3))) void*)l, 16, 0, 0);
}

// ---------------- RoPE cos/sin table: [S][16] ----------------
__global__ __launch_bounds__(256) void rope_table(float* __restrict__ rc, float* __restrict__ rs)
{
    int idx = blockIdx.x * 256 + threadIdx.x;   // S*16 threads
    int s = idx >> 4, i = idx & 15;
    float inv = powf(10000.0f, -(float)(2 * i) / 32.0f);
    float ang = (float)s * inv;
    rc[idx] = cosf(ang);
    rs[idx] = sinf(ang);
}

// ---------------- fp32 -> f16 conversion: WEIGHTS ONLY (8 MiB out) ----------------
__global__ __launch_bounds__(256) void cvt_w(
    const float* __restrict__ Wq, const float* __restrict__ Wk,
    const float* __restrict__ Wv, const float* __restrict__ Wo, f16* __restrict__ dst)
{
    const int z = blockIdx.y;
    const float* src = (z == 0) ? Wq : (z == 1) ? Wk : (z == 2) ? Wv : Wo;
    const size_t off = (size_t)z * 1048576;
    int i = blockIdx.x * 256 + threadIdx.x;     // 512 blocks * 256 = 131072 octets exact
    const float4* s = reinterpret_cast<const float4*>(src) + (size_t)i * 2;
    float4 v0 = s[0], v1 = s[1];
    f16x8 h = { (f16)v0.x, (f16)v0.y, (f16)v0.z, (f16)v0.w,
                (f16)v1.x, (f16)v1.y, (f16)v1.z, (f16)v1.w };
    reinterpret_cast<f16x8*>(dst + off)[i] = h;
}

// ---------------- projection GEMM: fp32 X via gload_lds + cvt-on-read; f16 W ----------------
// T1 XCD-chunked swizzle: grid 768 = all blocks co-resident (3/CU); swz gives each XCD a
// contiguous 96-tile chunk (3 W-panels, L2-resident; X-slab readers co-located).
// A LDS: fp32 [128][32], slot-XOR swizzle (slot' = slot ^ (row&7)); pre-swizzled source.
// q scaled by (1/8)*log2(e); q,k stored (B,H,S,hd); v stored transposed (B,H,hd,S)
__global__ __launch_bounds__(256) void proj_gemm_h(
    const float* __restrict__ Xq, const float* __restrict__ Xk, const float* __restrict__ Xv,
    const f16* __restrict__ Wq, const f16* __restrict__ Wk, const f16* __restrict__ Wv,
    const float* __restrict__ bq, const float* __restrict__ bk, const float* __restrict__ bv,
    f16* __restrict__ qo, f16* __restrict__ ko, f16* __restrict__ vo,
    const float* __restrict__ rc, const float* __restrict__ rs)
{
    // XCD swizzle (bijective: 768 % 8 == 0): lin = x + 32*y + 256*z
    const int lin = blockIdx.x + 32 * (blockIdx.y + 8 * blockIdx.z);
    const int swz = (lin & 7) * 96 + (lin >> 3);
    const int bx = swz & 31;
    const int by = (swz >> 5) & 7;
    const int mode = swz >> 8;              // 0=q 1=k 2=v

    const float* X   = (mode == 0) ? Xq : (mode == 1) ? Xk : Xv;
    const f16* W     = (mode == 0) ? Wq : (mode == 1) ? Wk : Wv;
    const float* bias = (mode == 0) ? bq : (mode == 1) ? bk : bv;

    __shared__ __align__(16) float Afp[128 * 32];   // 16 KiB
    __shared__ __align__(16) f16   Bl[128 * 32];    // 8 KiB

    const int t = threadIdx.x, lane = t & 63, wid = t >> 6;
    const int q15 = lane & 15, g = lane >> 4;
    const int wr = wid >> 1, wc = wid & 1;
    const int m0 = bx * 128, n0 = by * 128;

    // A staging: 4 insts/wave, each covers 8 rows (8 fp32-slots of 4); source pre-swizzled
    const int srowA = wid * 32 + (lane >> 3);            // +8 per inst
    const int sslotA = (lane & 7) ^ (lane >> 3);         // row&7 == lane>>3
    const float* XgA = X + (size_t)(m0 + srowA) * DMODEL + sslotA * 4;
    float* aB0 = &Afp[(wid * 32 + 0) * 32];
    float* aB1 = &Afp[(wid * 32 + 8) * 32];
    float* aB2 = &Afp[(wid * 32 + 16) * 32];
    float* aB3 = &Afp[(wid * 32 + 24) * 32];

    // B staging: f16, 2 insts/wave (m97 pattern)
    const int srowB = wid * 16 + (lane >> 2);
    const int scolB = (lane & 3) * 8;
    const f16* Wg = W + (size_t)(n0 + srowB) * DMODEL + scolB;
    f16* bl0 = &Bl[(wid * 16) * 32];
    f16* bl1 = &Bl[(wid * 16 + 64) * 32];

    f32x4 acc[4][4];
    #pragma unroll
    for (int m = 0; m < 4; m++)
        #pragma unroll
        for (int n = 0; n < 4; n++)
            acc[m][n] = f32x4{0.f, 0.f, 0.f, 0.f};

    for (int k0 = 0; k0 < DMODEL; k0 += 32) {
        __syncthreads();
        gload16(XgA + k0, aB0);
        gload16(XgA + (size_t)8 * DMODEL + k0, aB1);
        gload16(XgA + (size_t)16 * DMODEL + k0, aB2);
        gload16(XgA + (size_t)24 * DMODEL + k0, aB3);
        gload16(Wg + k0, bl0);
        gload16(Wg + (size_t)64 * DMODEL + k0, bl1);
        __syncthreads();

        f16x8 a[4], b[4];
        const int p = q15 & 7;
        #pragma unroll
        for (int m = 0; m < 4; m++) {
            const float* ap = &Afp[(wr * 64 + m * 16 + q15) * 32];
            float4 v0 = *reinterpret_cast<const float4*>(&ap[((2 * g) ^ p) * 4]);
            float4 v1 = *reinterpret_cast<const float4*>(&ap[((2 * g + 1) ^ p) * 4]);
            a[m] = f16x8{ (f16)v0.x, (f16)v0.y, (f16)v0.z, (f16)v0.w,
                          (f16)v1.x, (f16)v1.y, (f16)v1.z, (f16)v1.w };
        }
        #pragma unroll
        for (int n = 0; n < 4; n++)
            b[n] = *reinterpret_cast<const f16x8*>(&Bl[(wc * 64 + n * 16 + q15) * 32 + g * 8]);
        #pragma unroll
        for (int m = 0; m < 4; m++)
            #pragma unroll
            for (int n = 0; n < 4; n++)
                acc[m][n] = __builtin_amdgcn_mfma_f32_16x16x32_f16(a[m], b[n], acc[m][n], 0, 0, 0);
    }

    const int rowb = m0 + wr * 64, colb = n0 + wc * 64;
    #pragma unroll
    for (int n = 0; n < 4; n++) {
        int cN = colb + n * 16 + q15;
        float bvv = bias[cN];
        int h = cN >> 6, d = cN & 63;
        #pragma unroll
        for (int m = 0; m < 4; m++) {
            #pragma unroll
            for (int rg = 0; rg < 4; rg++) {
                int r = rowb + m * 16 + g * 4 + rg;
                int s = r >> 1, bi = r & 1;
                float val = acc[m][n][rg] + bvv;
                if (mode < 2) {
                    float pv = __shfl_xor(val, 1);
                    if (d < 32) {
                        int fi = d >> 1;
                        float cc = rc[s * 16 + fi], ss = rs[s * 16 + fi];
                        val = ((d & 1) == 0) ? val * cc - pv * ss : val * cc + pv * ss;
                    }
                    if (mode == 0) val *= 0.18033688f;      // (1/8)*log2(e)
                    ((mode == 0) ? qo : ko)[(((size_t)bi * NHEADS + h) * S_LEN + s) * HD + d] = (f16)val;
                } else {
                    vo[(((size_t)bi * NHEADS + h) * HD + d) * S_LEN + s] = (f16)val;
                }
            }
        }
    }
}

// ---------------- f16-input output GEMM, global_load_lds staging ----------------
__global__ __launch_bounds__(256) void out_gemm_h(
    const f16* __restrict__ X, const f16* __restrict__ W,
    const float* __restrict__ bias, float* __restrict__ out)
{
    __shared__ __align__(16) f16 Al[128 * 32];
    __shared__ __align__(16) f16 Bl[128 * 32];

    const int t = threadIdx.x, lane = t & 63, wid = t >> 6;
    const int q15 = lane & 15, g = lane >> 4;
    const int wr = wid >> 1, wc = wid & 1;
    const int m0 = blockIdx.x * 128, n0 = blockIdx.y * 128;

    const int srow = wid * 16 + (lane >> 2);
    const int scol = (lane & 3) * 8;
    const f16* Xg = X + (size_t)(m0 + srow) * DMODEL + scol;
    const f16* Wg = W + (size_t)(n0 + srow) * DMODEL + scol;
    f16* al0 = &Al[(wid * 16) * 32];
    f16* al1 = &Al[(wid * 16 + 64) * 32];
    f16* bl0 = &Bl[(wid * 16) * 32];
    f16* bl1 = &Bl[(wid * 16 + 64) * 32];

    f32x4 acc[4][4];
    #pragma unroll
    for (int m = 0; m < 4; m++)
        #pragma unroll
        for (int n = 0; n < 4; n++)
            acc[m][n] = f32x4{0.f, 0.f, 0.f, 0.f};

    for (int k0 = 0; k0 < DMODEL; k0 += 32) {
        __syncthreads();
        gload16(Xg + k0, al0);
        gload16(Xg + (size_t)64 * DMODEL + k0, al1);
        gload16(Wg + k0, bl0);
        gload16(Wg + (size_t)64 * DMODEL + k0, bl1);
        __syncthreads();

        f16x8 a[4], b[4];
        #pragma unroll
        for (int m = 0; m < 4; m++)
            a[m] = *reinterpret_cast<const f16x8*>(&Al[(wr * 64 + m * 16 + q15) * 32 + g * 8]);
        #pragma unroll
        for (int n = 0; n < 4; n++)
            b[n] = *reinterpret_cast<const f16x8*>(&Bl[(wc * 64 + n * 16 + q15) * 32 + g * 8]);
        #pragma unroll
        for (int m = 0; m < 4; m++)
            #pragma unroll
            for (int n = 0; n < 4; n++)
                acc[m][n] = __builtin_amdgcn_mfma_f32_16x16x32_f16(a[m], b[n], acc[m][n], 0, 0, 0);
    }

    const int rowb = m0 + wr * 64, colb = n0 + wc * 64;
    #pragma unroll
    for (int n = 0; n < 4; n++) {
        int cN = colb + n * 16 + q15;
        float bvv = bias[cN];
        #pragma unroll
        for (int m = 0; m < 4; m++) {
            #pragma unroll
            for (int rg = 0; rg < 4; rg++) {
                int r = rowb + m * 16 + g * 4 + rg;
                out[(size_t)r * DMODEL + cN] = acc[m][n][rg] + bvv;
            }
        }
    }
}

// ---------------- FALLBACK: fp32-input projection GEMM (reg-staged) ----------------
__global__ __launch_bounds__(256) void proj_gemm(
    const float* __restrict__ Xq, const float* __restrict__ Xk, const float* __restrict__ Xv,
    const float* __restrict__ Wq, const float* __restrict__ Wk, const float* __restrict__ Wv,
    const float* __restrict__ bq, const float* __restrict__ bk, const float* __restrict__ bv,
    f16* __restrict__ qo, f16* __restrict__ ko, f16* __restrict__ vo,
    const float* __restrict__ rc, const float* __restrict__ rs)
{
    const int mode = blockIdx.z;
    const float* X    = (mode == 0) ? Xq : (mode == 1) ? Xk : Xv;
    const float* W    = (mode == 0) ? Wq : (mode == 1) ? Wk : Wv;
    const float* bias = (mode == 0) ? bq : (mode == 1) ? bk : bv;

    __shared__ f16 Al[128 * 40];
    __shared__ f16 Bl[128 * 40];

    const int t = threadIdx.x;
    const int lane = t & 63, wid = t >> 6;
    const int wr = wid >> 1, wc = wid & 1;
    const int m0 = blockIdx.x * 128, n0 = blockIdx.y * 128;

    f32x4 acc[4][4];
    #pragma unroll
    for (int m = 0; m < 4; m++)
        #pragma unroll
        for (int n = 0; n < 4; n++)
            acc[m][n] = f32x4{0.f, 0.f, 0.f, 0.f};

    for (int k0 = 0; k0 < DMODEL; k0 += 32) {
        __syncthreads();
        #pragma unroll
        for (int i = 0; i < 2; i++) {
            int e = (i * 256 + t) * 8;
            int r = e >> 5, c = e & 31;
            {
                const float* src = &X[(size_t)(m0 + r) * DMODEL + k0 + c];
                float4 v0 = *reinterpret_cast<const float4*>(src);
                float4 v1 = *reinterpret_cast<const float4*>(src + 4);
                f16x8 h = { (f16)v0.x, (f16)v0.y, (f16)v0.z, (f16)v0.w,
                            (f16)v1.x, (f16)v1.y, (f16)v1.z, (f16)v1.w };
                *reinterpret_cast<f16x8*>(&Al[r * 40 + c]) = h;
            }
            {
                const float* src = &W[(size_t)(n0 + r) * DMODEL + k0 + c];
                float4 v0 = *reinterpret_cast<const float4*>(src);
                float4 v1 = *reinterpret_cast<const float4*>(src + 4);
                f16x8 h = { (f16)v0.x, (f16)v0.y, (f16)v0.z, (f16)v0.w,
                            (f16)v1.x, (f16)v1.y, (f16)v1.z, (f16)v1.w };
                *reinterpret_cast<f16x8*>(&Bl[r * 40 + c]) = h;
            }
        }
        __syncthreads();
        f16x8 a[4], b[4];
        #pragma unroll
        for (int m = 0; m < 4; m++)
            a[m] = *reinterpret_cast<const f16x8*>(&Al[(wr * 64 + m * 16 + (lane & 15)) * 40 + (lane >> 4) * 8]);
        #pragma unroll
        for (int n = 0; n < 4; n++)
            b[n] = *reinterpret_cast<const f16x8*>(&Bl[(wc * 64 + n * 16 + (lane & 15)) * 40 + (lane >> 4) * 8]);
        #pragma unroll
        for (int m = 0; m < 4; m++)
            #pragma unroll
            for (int n = 0; n < 4; n++)
                acc[m][n] = __builtin_amdgcn_mfma_f32_16x16x32_f16(a[m], b[n], acc[m][n], 0, 0, 0);
    }

    const int rowb = m0 + wr * 64, colb = n0 + wc * 64;
    #pragma unroll
    for (int n = 0; n < 4; n++) {
        int cN = colb + n * 16 + (lane & 15);
        float bvv = bias[cN];
        int h = cN >> 6, d = cN & 63;
        #pragma unroll
        for (int m = 0; m < 4; m++) {
            #pragma unroll
            for (int rg = 0; rg < 4; rg++) {
                int r = rowb + m * 16 + (lane >> 4) * 4 + rg;
                int s = r >> 1, bi = r & 1;
                float val = acc[m][n][rg] + bvv;
                if (mode < 2) {
                    float pv = __shfl_xor(val, 1);
                    if (d < 32) {
                        int fi = d >> 1;
                        float cc = rc[s * 16 + fi], ss = rs[s * 16 + fi];
                        val = ((d & 1) == 0) ? val * cc - pv * ss : val * cc + pv * ss;
                    }
                    if (mode == 0) val *= 0.18033688f;
                    ((mode == 0) ? qo : ko)[(((size_t)bi * NHEADS + h) * S_LEN + s) * HD + d] = (f16)val;
                } else {
                    vo[(((size_t)bi * NHEADS + h) * HD + d) * S_LEN + s] = (f16)val;
                }
            }
        }
    }
}

// ---------------- FALLBACK: output projection ----------------
__global__ __launch_bounds__(256) void out_gemm(
    const f16* __restrict__ X, const float* __restrict__ W,
    const float* __restrict__ bias, float* __restrict__ out)
{
    __shared__ f16 Al[128 * 40];
    __shared__ f16 Bl[128 * 40];

    const int t = threadIdx.x;
    const int lane = t & 63, wid = t >> 6;
    const int wr = wid >> 1, wc = wid & 1;
    const int m0 = blockIdx.x * 128, n0 = blockIdx.y * 128;

    f32x4 acc[4][4];
    #pragma unroll
    for (int m = 0; m < 4; m++)
        #pragma unroll
        for (int n = 0; n < 4; n++)
            acc[m][n] = f32x4{0.f, 0.f, 0.f, 0.f};

    for (int k0 = 0; k0 < DMODEL; k0 += 32) {
        __syncthreads();
        #pragma unroll
        for (int i = 0; i < 2; i++) {
            int e = (i * 256 + t) * 8;
            int r = e >> 5, c = e & 31;
            *reinterpret_cast<uint4*>(&Al[r * 40 + c]) =
                *reinterpret_cast<const uint4*>(&X[(size_t)(m0 + r) * DMODEL + k0 + c]);
            {
                const float* src = &W[(size_t)(n0 + r) * DMODEL + k0 + c];
                float4 v0 = *reinterpret_cast<const float4*>(src);
                float4 v1 = *reinterpret_cast<const float4*>(src + 4);
                f16x8 h = { (f16)v0.x, (f16)v0.y, (f16)v0.z, (f16)v0.w,
                            (f16)v1.x, (f16)v1.y, (f16)v1.z, (f16)v1.w };
                *reinterpret_cast<f16x8*>(&Bl[r * 40 + c]) = h;
            }
        }
        __syncthreads();
        f16x8 a[4], b[4];
        #pragma unroll
        for (int m = 0; m < 4; m++)
            a[m] = *reinterpret_cast<const f16x8*>(&Al[(wr * 64 + m * 16 + (lane & 15)) * 40 + (lane >> 4) * 8]);
        #pragma unroll
        for (int n = 0; n < 4; n++)
            b[n] = *reinterpret_cast<const f16x8*>(&Bl[(wc * 64 + n * 16 + (lane & 15)) * 40 + (lane >> 4) * 8]);
        #pragma unroll
        for (int m = 0; m < 4; m++)
            #pragma unroll
            for (int n = 0; n < 4; n++)
                acc[m][n] = __builtin_amdgcn_mfma_f32_16x16x32_f16(a[m], b[n], acc[m][n], 0, 0, 0);
    }

    const int rowb = m0 + wr * 64, colb = n0 + wc * 64;
    #pragma unroll
    for (int n = 0; n < 4; n++) {
        int cN = colb + n * 16 + (lane & 15);
        float bvv = bias[cN];
        #pragma unroll
        for (int m = 0; m < 4; m++) {
            #pragma unroll
            for (int rg = 0; rg < 4; rg++) {
                int r = rowb + m * 16 + (lane >> 4) * 4 + rg;
                out[(size_t)r * DMODEL + cN] = acc[m][n][rg] + bvv;
            }
        }
    }
}

// ---------------- flash attention: deferred-PV pipeline (unchanged) ----------------
__global__ __launch_bounds__(512) void attn_fwd(
    const f16* __restrict__ qb, const f16* __restrict__ kb,
    const f16* __restrict__ vt, f16* __restrict__ ctx)
{
    __shared__ f16 Kl[2][64 * 64];
    __shared__ f16 Vl[3][64 * 64];
    __shared__ f16 Pl[2][8 * 16 * LD];

    const int t = threadIdx.x, lane = t & 63, wid = t >> 6;
    const int q15 = lane & 15, g = lane >> 4;
    const int sw = q15 & 7;                 // read-side XOR key
    const int bh = blockIdx.y;
    const int q0 = blockIdx.x * 128 + wid * 16;

    const f16* qptr = qb + ((size_t)bh * S_LEN + q0) * HD;
    f16x8 qf0 = *reinterpret_cast<const f16x8*>(&qptr[q15 * HD + g * 8]);
    f16x8 qf1 = *reinterpret_cast<const f16x8*>(&qptr[q15 * HD + g * 8 + 32]);

    f32x4 ctxa[4];
    #pragma unroll
    for (int i = 0; i < 4; i++) ctxa[i] = f32x4{0.f, 0.f, 0.f, 0.f};
    float mrun = -3.0e38f, lrun = 0.f;

    const int srow = t >> 3;
    const int sslot = (t & 7) ^ (srow & 7);
    const f16* kg = kb + (size_t)bh * S_LEN * HD + (size_t)srow * HD + sslot * 8;
    const f16* vg = vt + (size_t)bh * HD * S_LEN + (size_t)srow * S_LEN + sslot * 8;
    const int lds_wbase = wid * 512;
    const int poff = wid * (16 * LD);

    gload16(kg, &Kl[0][lds_wbase]);
    gload16(vg, &Vl[0][lds_wbase]);
    __syncthreads();

    int kbuf = 0;
    int vprev = 2, vcur = 0, vnext = 1;

    for (int kt = 0; kt < NT; kt++) {
        if (kt + 1 < NT) {
            gload16(kg + (size_t)(kt + 1) * 64 * HD, &Kl[kbuf ^ 1][lds_wbase]);
            gload16(vg + (size_t)(kt + 1) * 64,      &Vl[vnext][lds_wbase]);
        }
        const f16* Kc = Kl[kbuf];

        f32x4 sc[4];
        __builtin_amdgcn_s_setprio(1);
        #pragma unroll
        for (int f = 0; f < 4; f++) {
            f16x8 kf0 = *reinterpret_cast<const f16x8*>(&Kc[(f * 16 + q15) * 64 + ((g ^ sw) * 8)]);
            f16x8 kf1 = *reinterpret_cast<const f16x8*>(&Kc[(f * 16 + q15) * 64 + (((g + 4) ^ sw) * 8)]);
            f32x4 z = {0.f, 0.f, 0.f, 0.f};
            z = __builtin_amdgcn_mfma_f32_16x16x32_f16(kf0, qf0, z, 0, 0, 0);
            sc[f] = __builtin_amdgcn_mfma_f32_16x16x32_f16(kf1, qf1, z, 0, 0, 0);
        }
        if (kt > 0) {
            const f16* Vp = Vl[vprev];
            const f16* pr = &Pl[(kt & 1) ^ 1][poff];
            #pragma unroll
            for (int c = 0; c < 2; c++) {
                f16x8 pfr = *reinterpret_cast<const f16x8*>(&pr[q15 * LD + g * 8 + c * 32]);
                #pragma unroll
                for (int n = 0; n < 4; n++) {
                    f16x8 vf = *reinterpret_cast<const f16x8*>(&Vp[(n * 16 + q15) * 64 + (((g + c * 4) ^ sw) * 8)]);
                    ctxa[n] = __builtin_amdgcn_mfma_f32_16x16x32_f16(vf, pfr, ctxa[n], 0, 0, 0);
                }
            }
        }
        __builtin_amdgcn_s_setprio(0);

        float pmf[4];
        #pragma unroll
        for (int f = 0; f < 4; f++)
            pmf[f] = fmaxf(fmaxf(sc[f][0], sc[f][1]), fmaxf(sc[f][2], sc[f][3]));
        float pm = fmaxf(fmaxf(pmf[0], pmf[1]), fmaxf(pmf[2], pmf[3]));
        if (!__all(pm - mrun <= 8.0f)) {
            float pmax = fmaxf(pm, __shfl_xor(pm, 16));
            pmax = fmaxf(pmax, __shfl_xor(pmax, 32));
            float mnew = fmaxf(mrun, pmax);
            float scale = __builtin_amdgcn_exp2f(mrun - mnew);
            lrun *= scale;
            #pragma unroll
            for (int n = 0; n < 4; n++) {
                ctxa[n][0] *= scale; ctxa[n][1] *= scale;
                ctxa[n][2] *= scale; ctxa[n][3] *= scale;
            }
            mrun = mnew;
        }
        float tsum = 0.f;
        #pragma unroll
        for (int f = 0; f < 4; f++)
            #pragma unroll
            for (int rg = 0; rg < 4; rg++) {
                float p = __builtin_amdgcn_exp2f(sc[f][rg] - mrun);
                sc[f][rg] = p;
                tsum += p;
            }
        lrun += tsum;

        f16* pw = &Pl[kt & 1][poff];
        #pragma unroll
        for (int f = 0; f < 4; f++) {
            f16x4 pwv = { (f16)sc[f][0], (f16)sc[f][1], (f16)sc[f][2], (f16)sc[f][3] };
            *reinterpret_cast<f16x4*>(&pw[q15 * LD + f * 16 + g * 4]) = pwv;
        }

        __syncthreads();
        kbuf ^= 1;
        int tmp = vprev; vprev = vcur; vcur = vnext; vnext = tmp;
    }

    // epilogue: PV(NT-1)
    {
        const f16* Vp = Vl[vprev];
        const f16* pr = &Pl[(NT - 1) & 1][poff];
        #pragma unroll
        for (int c = 0; c < 2; c++) {
            f16x8 pfr = *reinterpret_cast<const f16x8*>(&pr[q15 * LD + g * 8 + c * 32]);
            #pragma unroll
            for (int n = 0; n < 4; n++) {
                f16x8 vf = *reinterpret_cast<const f16x8*>(&Vp[(n * 16 + q15) * 64 + (((g + c * 4) ^ sw) * 8)]);
                ctxa[n] = __builtin_amdgcn_mfma_f32_16x16x32_f16(vf, pfr, ctxa[n], 0, 0, 0);
            }
        }
    }

    lrun += __shfl_xor(lrun, 16);
    lrun += __shfl_xor(lrun, 32);
    const int bi = bh >> 4, h = bh & 15;
    const int s = q0 + q15;
    float inv = 1.0f / lrun;
    f16* outp = &ctx[((size_t)s * BATCH + bi) * DMODEL + h * HD];
    #pragma unroll
    for (int n = 0; n < 4; n++) {
        f16x4 o = { (f16)(ctxa[n][0] * inv), (f16)(ctxa[n][1] * inv),
                    (f16)(ctxa[n][2] * inv), (f16)(ctxa[n][3] * inv) };
        *reinterpret_cast<f16x4*>(&outp[n * 16 + g * 4]) = o;
    }
}

// ---------------- launch ----------------
extern "C" void kernel_launch(void* const* d_in, const int* in_sizes, int n_in,
                              void* d_out, int out_size, void* d_ws, size_t ws_size,
                              hipStream_t stream)
{
    const float* Q  = (const float*)d_in[0];
    const float* K  = (const float*)d_in[1];
    const float* V  = (const float*)d_in[2];
    const float* Wq = (const float*)d_in[3];
    const float* bq = (const float*)d_in[4];
    const float* Wk = (const float*)d_in[5];
    const float* bk = (const float*)d_in[6];
    const float* Wv = (const float*)d_in[7];
    const float* bv = (const float*)d_in[8];
    const float* Wo = (const float*)d_in[9];
    const float* bo = (const float*)d_in[10];
    float* out = (float*)d_out;

    char* w = (char*)d_ws;
    const size_t MBc = 1024 * 1024;
    const size_t NEED_FAST = 40 * MBc + 256 * 1024;   // 40.25 MiB

    if (ws_size >= NEED_FAST) {
        // FAST layout:
        //   [0,8M)       f16 weights: Wq,Wk,Wv,Wo (2M ea)
        //   [8M,8.25M)   rc, rs
        //   [8.25M,40.25M) qbuf, kbuf, vtb, ctxb (8M ea)
        f16* Wqh = (f16*)w;
        f16* Wkh = Wqh + 1048576;
        f16* Wvh = Wqh + 2097152;
        f16* Woh = Wqh + 3145728;
        float* rc = (float*)(w + 8 * MBc);
        float* rs = rc + 32768;
        f16* qbuf = (f16*)(w + 8 * MBc + 256 * 1024);
        f16* kbuf = qbuf + 4194304;
        f16* vtb  = kbuf + 4194304;
        f16* ctxb = vtb + 4194304;

        rope_table<<<(S_LEN * 16) / 256, 256, 0, stream>>>(rc, rs);
        cvt_w<<<dim3(512, 4), 256, 0, stream>>>(Wq, Wk, Wv, Wo, Wqh);
        proj_gemm_h<<<dim3(MROWS / 128, DMODEL / 128, 3), 256, 0, stream>>>(
            Q, K, V, Wqh, Wkh, Wvh, bq, bk, bv, qbuf, kbuf, vtb, rc, rs);
        attn_fwd<<<dim3(S_LEN / 128, BATCH * NHEADS), 512, 0, stream>>>(qbuf, kbuf, vtb, ctxb);
        out_gemm_h<<<dim3(MROWS / 128, DMODEL / 128), 256, 0, stream>>>(ctxb, Woh, bo, out);
    } else {
        const size_t szT = (size_t)S_LEN * 16 * sizeof(float);
        const size_t szQ = (size_t)MROWS * DMODEL * sizeof(f16);
        float* rc  = (float*)(w);
        float* rs  = (float*)(w + szT);
        f16* qbuf = (f16*)(w + 2 * szT);
        f16* kbuf = (f16*)(w + 2 * szT + szQ);
        f16* vtb  = (f16*)(w + 2 * szT + 2 * szQ);
        f16* ctxb = (f16*)(w + 2 * szT + 3 * szQ);

        rope_table<<<(S_LEN * 16) / 256, 256, 0, stream>>>(rc, rs);
        proj_gemm<<<dim3(MROWS / 128, DMODEL / 128, 3), 256, 0, stream>>>(
            Q, K, V, Wq, Wk, Wv, bq, bk, bv, qbuf, kbuf, vtb, rc, rs);
        attn_fwd<<<dim3(S_LEN / 128, BATCH * NHEADS), 512, 0, stream>>>(qbuf, kbuf, vtb, ctxb);
        out_gemm<<<dim3(MROWS / 128, DMODEL / 128), 256, 0, stream>>>(ctxb, Wo, bo, out);
    }
}

// Round 28
// 145.950 us; speedup vs baseline: 1.1807x; 1.1807x over previous
//
#include <hip/hip_runtime.h>
#include <hip/hip_bf16.h>
#include <hip/hip_fp16.h>

#define S_LEN  2048
#define BATCH  2
#define DMODEL 1024
#define NHEADS 16
#define HD     64
#define MROWS  4096   // S*B
#define LD     72     // attn P LDS stride (padded, per-wave)
#define NT     (S_LEN / 64)

using f16 = _Float16;
typedef __attribute__((ext_vector_type(8))) _Float16 f16x8;
typedef __attribute__((ext_vector_type(4))) _Float16 f16x4;
typedef __attribute__((ext_vector_type(4))) float    f32x4;

// async global->LDS, 16B per lane; LDS dest = wave-uniform base + lane*16
__device__ __forceinline__ void gload16(const void* g, void* l)
{
    __builtin_amdgcn_global_load_lds((const __attribute__((address_space(1))) void*)g,
                                     (__attribute__((address_space(3))) void*)l, 16, 0, 0);
}

// ---------------- RoPE cos/sin table: [S][16] ----------------
__global__ __launch_bounds__(256) void rope_table(float* __restrict__ rc, float* __restrict__ rs)
{
    int idx = blockIdx.x * 256 + threadIdx.x;   // S*16 threads
    int s = idx >> 4, i = idx & 15;
    float inv = powf(10000.0f, -(float)(2 * i) / 32.0f);
    float ang = (float)s * inv;
    rc[idx] = cosf(ang);
    rs[idx] = sinf(ang);
}

// ---------------- fp32 -> f16 conversion: WEIGHTS ONLY (8 MiB out) ----------------
__global__ __launch_bounds__(256) void cvt_w(
    const float* __restrict__ Wq, const float* __restrict__ Wk,
    const float* __restrict__ Wv, const float* __restrict__ Wo, f16* __restrict__ dst)
{
    const int z = blockIdx.y;
    const float* src = (z == 0) ? Wq : (z == 1) ? Wk : (z == 2) ? Wv : Wo;
    const size_t off = (size_t)z * 1048576;
    int i = blockIdx.x * 256 + threadIdx.x;     // 512 blocks * 256 = 131072 octets exact
    const float4* s = reinterpret_cast<const float4*>(src) + (size_t)i * 2;
    float4 v0 = s[0], v1 = s[1];
    f16x8 h = { (f16)v0.x, (f16)v0.y, (f16)v0.z, (f16)v0.w,
                (f16)v1.x, (f16)v1.y, (f16)v1.z, (f16)v1.w };
    reinterpret_cast<f16x8*>(dst + off)[i] = h;
}

// ---------------- projection GEMM: fp32 X via gload_lds + cvt-on-read; f16 W ----------------
// A LDS: fp32 [128][32], slot-XOR swizzle (slot' = slot ^ (row&7), slot = 4-fp32 group).
// Pre-swizzled global source; fragment read applies same XOR then converts to f16.
// q scaled by (1/8)*log2(e); q,k stored (B,H,S,hd); v stored transposed (B,H,hd,S)
__global__ __launch_bounds__(256) void proj_gemm_h(
    const float* __restrict__ Xq, const float* __restrict__ Xk, const float* __restrict__ Xv,
    const f16* __restrict__ Wq, const f16* __restrict__ Wk, const f16* __restrict__ Wv,
    const float* __restrict__ bq, const float* __restrict__ bk, const float* __restrict__ bv,
    f16* __restrict__ qo, f16* __restrict__ ko, f16* __restrict__ vo,
    const float* __restrict__ rc, const float* __restrict__ rs)
{
    const int mode = blockIdx.z;            // 0=q 1=k 2=v
    const float* X   = (mode == 0) ? Xq : (mode == 1) ? Xk : Xv;
    const f16* W     = (mode == 0) ? Wq : (mode == 1) ? Wk : Wv;
    const float* bias = (mode == 0) ? bq : (mode == 1) ? bk : bv;

    __shared__ __align__(16) float Afp[128 * 32];   // 16 KiB
    __shared__ __align__(16) f16   Bl[128 * 32];    // 8 KiB

    const int t = threadIdx.x, lane = t & 63, wid = t >> 6;
    const int q15 = lane & 15, g = lane >> 4;
    const int wr = wid >> 1, wc = wid & 1;
    const int m0 = blockIdx.x * 128, n0 = blockIdx.y * 128;

    // A staging: 4 insts/wave, each covers 8 rows (8 fp32-slots of 4); source pre-swizzled
    const int srowA = wid * 32 + (lane >> 3);            // +8 per inst
    const int sslotA = (lane & 7) ^ (lane >> 3);         // row&7 == lane>>3
    const float* XgA = X + (size_t)(m0 + srowA) * DMODEL + sslotA * 4;
    float* aB0 = &Afp[(wid * 32 + 0) * 32];
    float* aB1 = &Afp[(wid * 32 + 8) * 32];
    float* aB2 = &Afp[(wid * 32 + 16) * 32];
    float* aB3 = &Afp[(wid * 32 + 24) * 32];

    // B staging: f16, 2 insts/wave (m97 pattern)
    const int srowB = wid * 16 + (lane >> 2);
    const int scolB = (lane & 3) * 8;
    const f16* Wg = W + (size_t)(n0 + srowB) * DMODEL + scolB;
    f16* bl0 = &Bl[(wid * 16) * 32];
    f16* bl1 = &Bl[(wid * 16 + 64) * 32];

    f32x4 acc[4][4];
    #pragma unroll
    for (int m = 0; m < 4; m++)
        #pragma unroll
        for (int n = 0; n < 4; n++)
            acc[m][n] = f32x4{0.f, 0.f, 0.f, 0.f};

    for (int k0 = 0; k0 < DMODEL; k0 += 32) {
        __syncthreads();
        gload16(XgA + k0, aB0);
        gload16(XgA + (size_t)8 * DMODEL + k0, aB1);
        gload16(XgA + (size_t)16 * DMODEL + k0, aB2);
        gload16(XgA + (size_t)24 * DMODEL + k0, aB3);
        gload16(Wg + k0, bl0);
        gload16(Wg + (size_t)64 * DMODEL + k0, bl1);
        __syncthreads();

        f16x8 a[4], b[4];
        const int p = q15 & 7;
        #pragma unroll
        for (int m = 0; m < 4; m++) {
            const float* ap = &Afp[(wr * 64 + m * 16 + q15) * 32];
            float4 v0 = *reinterpret_cast<const float4*>(&ap[((2 * g) ^ p) * 4]);
            float4 v1 = *reinterpret_cast<const float4*>(&ap[((2 * g + 1) ^ p) * 4]);
            a[m] = f16x8{ (f16)v0.x, (f16)v0.y, (f16)v0.z, (f16)v0.w,
                          (f16)v1.x, (f16)v1.y, (f16)v1.z, (f16)v1.w };
        }
        #pragma unroll
        for (int n = 0; n < 4; n++)
            b[n] = *reinterpret_cast<const f16x8*>(&Bl[(wc * 64 + n * 16 + q15) * 32 + g * 8]);
        #pragma unroll
        for (int m = 0; m < 4; m++)
            #pragma unroll
            for (int n = 0; n < 4; n++)
                acc[m][n] = __builtin_amdgcn_mfma_f32_16x16x32_f16(a[m], b[n], acc[m][n], 0, 0, 0);
    }

    const int rowb = m0 + wr * 64, colb = n0 + wc * 64;
    #pragma unroll
    for (int n = 0; n < 4; n++) {
        int cN = colb + n * 16 + q15;
        float bvv = bias[cN];
        int h = cN >> 6, d = cN & 63;
        #pragma unroll
        for (int m = 0; m < 4; m++) {
            #pragma unroll
            for (int rg = 0; rg < 4; rg++) {
                int r = rowb + m * 16 + g * 4 + rg;
                int s = r >> 1, bi = r & 1;
                float val = acc[m][n][rg] + bvv;
                if (mode < 2) {
                    float pv = __shfl_xor(val, 1);
                    if (d < 32) {
                        int fi = d >> 1;
                        float cc = rc[s * 16 + fi], ss = rs[s * 16 + fi];
                        val = ((d & 1) == 0) ? val * cc - pv * ss : val * cc + pv * ss;
                    }
                    if (mode == 0) val *= 0.18033688f;      // (1/8)*log2(e)
                    ((mode == 0) ? qo : ko)[(((size_t)bi * NHEADS + h) * S_LEN + s) * HD + d] = (f16)val;
                } else {
                    vo[(((size_t)bi * NHEADS + h) * HD + d) * S_LEN + s] = (f16)val;
                }
            }
        }
    }
}

// ---------------- f16-input output GEMM, global_load_lds staging ----------------
__global__ __launch_bounds__(256) void out_gemm_h(
    const f16* __restrict__ X, const f16* __restrict__ W,
    const float* __restrict__ bias, float* __restrict__ out)
{
    __shared__ __align__(16) f16 Al[128 * 32];
    __shared__ __align__(16) f16 Bl[128 * 32];

    const int t = threadIdx.x, lane = t & 63, wid = t >> 6;
    const int q15 = lane & 15, g = lane >> 4;
    const int wr = wid >> 1, wc = wid & 1;
    const int m0 = blockIdx.x * 128, n0 = blockIdx.y * 128;

    const int srow = wid * 16 + (lane >> 2);
    const int scol = (lane & 3) * 8;
    const f16* Xg = X + (size_t)(m0 + srow) * DMODEL + scol;
    const f16* Wg = W + (size_t)(n0 + srow) * DMODEL + scol;
    f16* al0 = &Al[(wid * 16) * 32];
    f16* al1 = &Al[(wid * 16 + 64) * 32];
    f16* bl0 = &Bl[(wid * 16) * 32];
    f16* bl1 = &Bl[(wid * 16 + 64) * 32];

    f32x4 acc[4][4];
    #pragma unroll
    for (int m = 0; m < 4; m++)
        #pragma unroll
        for (int n = 0; n < 4; n++)
            acc[m][n] = f32x4{0.f, 0.f, 0.f, 0.f};

    for (int k0 = 0; k0 < DMODEL; k0 += 32) {
        __syncthreads();
        gload16(Xg + k0, al0);
        gload16(Xg + (size_t)64 * DMODEL + k0, al1);
        gload16(Wg + k0, bl0);
        gload16(Wg + (size_t)64 * DMODEL + k0, bl1);
        __syncthreads();

        f16x8 a[4], b[4];
        #pragma unroll
        for (int m = 0; m < 4; m++)
            a[m] = *reinterpret_cast<const f16x8*>(&Al[(wr * 64 + m * 16 + q15) * 32 + g * 8]);
        #pragma unroll
        for (int n = 0; n < 4; n++)
            b[n] = *reinterpret_cast<const f16x8*>(&Bl[(wc * 64 + n * 16 + q15) * 32 + g * 8]);
        #pragma unroll
        for (int m = 0; m < 4; m++)
            #pragma unroll
            for (int n = 0; n < 4; n++)
                acc[m][n] = __builtin_amdgcn_mfma_f32_16x16x32_f16(a[m], b[n], acc[m][n], 0, 0, 0);
    }

    const int rowb = m0 + wr * 64, colb = n0 + wc * 64;
    #pragma unroll
    for (int n = 0; n < 4; n++) {
        int cN = colb + n * 16 + q15;
        float bvv = bias[cN];
        #pragma unroll
        for (int m = 0; m < 4; m++) {
            #pragma unroll
            for (int rg = 0; rg < 4; rg++) {
                int r = rowb + m * 16 + g * 4 + rg;
                out[(size_t)r * DMODEL + cN] = acc[m][n][rg] + bvv;
            }
        }
    }
}

// ---------------- FALLBACK: fp32-input projection GEMM (reg-staged) ----------------
__global__ __launch_bounds__(256) void proj_gemm(
    const float* __restrict__ Xq, const float* __restrict__ Xk, const float* __restrict__ Xv,
    const float* __restrict__ Wq, const float* __restrict__ Wk, const float* __restrict__ Wv,
    const float* __restrict__ bq, const float* __restrict__ bk, const float* __restrict__ bv,
    f16* __restrict__ qo, f16* __restrict__ ko, f16* __restrict__ vo,
    const float* __restrict__ rc, const float* __restrict__ rs)
{
    const int mode = blockIdx.z;
    const float* X    = (mode == 0) ? Xq : (mode == 1) ? Xk : Xv;
    const float* W    = (mode == 0) ? Wq : (mode == 1) ? Wk : Wv;
    const float* bias = (mode == 0) ? bq : (mode == 1) ? bk : bv;

    __shared__ f16 Al[128 * 40];
    __shared__ f16 Bl[128 * 40];

    const int t = threadIdx.x;
    const int lane = t & 63, wid = t >> 6;
    const int wr = wid >> 1, wc = wid & 1;
    const int m0 = blockIdx.x * 128, n0 = blockIdx.y * 128;

    f32x4 acc[4][4];
    #pragma unroll
    for (int m = 0; m < 4; m++)
        #pragma unroll
        for (int n = 0; n < 4; n++)
            acc[m][n] = f32x4{0.f, 0.f, 0.f, 0.f};

    for (int k0 = 0; k0 < DMODEL; k0 += 32) {
        __syncthreads();
        #pragma unroll
        for (int i = 0; i < 2; i++) {
            int e = (i * 256 + t) * 8;
            int r = e >> 5, c = e & 31;
            {
                const float* src = &X[(size_t)(m0 + r) * DMODEL + k0 + c];
                float4 v0 = *reinterpret_cast<const float4*>(src);
                float4 v1 = *reinterpret_cast<const float4*>(src + 4);
                f16x8 h = { (f16)v0.x, (f16)v0.y, (f16)v0.z, (f16)v0.w,
                            (f16)v1.x, (f16)v1.y, (f16)v1.z, (f16)v1.w };
                *reinterpret_cast<f16x8*>(&Al[r * 40 + c]) = h;
            }
            {
                const float* src = &W[(size_t)(n0 + r) * DMODEL + k0 + c];
                float4 v0 = *reinterpret_cast<const float4*>(src);
                float4 v1 = *reinterpret_cast<const float4*>(src + 4);
                f16x8 h = { (f16)v0.x, (f16)v0.y, (f16)v0.z, (f16)v0.w,
                            (f16)v1.x, (f16)v1.y, (f16)v1.z, (f16)v1.w };
                *reinterpret_cast<f16x8*>(&Bl[r * 40 + c]) = h;
            }
        }
        __syncthreads();
        f16x8 a[4], b[4];
        #pragma unroll
        for (int m = 0; m < 4; m++)
            a[m] = *reinterpret_cast<const f16x8*>(&Al[(wr * 64 + m * 16 + (lane & 15)) * 40 + (lane >> 4) * 8]);
        #pragma unroll
        for (int n = 0; n < 4; n++)
            b[n] = *reinterpret_cast<const f16x8*>(&Bl[(wc * 64 + n * 16 + (lane & 15)) * 40 + (lane >> 4) * 8]);
        #pragma unroll
        for (int m = 0; m < 4; m++)
            #pragma unroll
            for (int n = 0; n < 4; n++)
                acc[m][n] = __builtin_amdgcn_mfma_f32_16x16x32_f16(a[m], b[n], acc[m][n], 0, 0, 0);
    }

    const int rowb = m0 + wr * 64, colb = n0 + wc * 64;
    #pragma unroll
    for (int n = 0; n < 4; n++) {
        int cN = colb + n * 16 + (lane & 15);
        float bvv = bias[cN];
        int h = cN >> 6, d = cN & 63;
        #pragma unroll
        for (int m = 0; m < 4; m++) {
            #pragma unroll
            for (int rg = 0; rg < 4; rg++) {
                int r = rowb + m * 16 + (lane >> 4) * 4 + rg;
                int s = r >> 1, bi = r & 1;
                float val = acc[m][n][rg] + bvv;
                if (mode < 2) {
                    float pv = __shfl_xor(val, 1);
                    if (d < 32) {
                        int fi = d >> 1;
                        float cc = rc[s * 16 + fi], ss = rs[s * 16 + fi];
                        val = ((d & 1) == 0) ? val * cc - pv * ss : val * cc + pv * ss;
                    }
                    if (mode == 0) val *= 0.18033688f;
                    ((mode == 0) ? qo : ko)[(((size_t)bi * NHEADS + h) * S_LEN + s) * HD + d] = (f16)val;
                } else {
                    vo[(((size_t)bi * NHEADS + h) * HD + d) * S_LEN + s] = (f16)val;
                }
            }
        }
    }
}

// ---------------- FALLBACK: output projection ----------------
__global__ __launch_bounds__(256) void out_gemm(
    const f16* __restrict__ X, const float* __restrict__ W,
    const float* __restrict__ bias, float* __restrict__ out)
{
    __shared__ f16 Al[128 * 40];
    __shared__ f16 Bl[128 * 40];

    const int t = threadIdx.x;
    const int lane = t & 63, wid = t >> 6;
    const int wr = wid >> 1, wc = wid & 1;
    const int m0 = blockIdx.x * 128, n0 = blockIdx.y * 128;

    f32x4 acc[4][4];
    #pragma unroll
    for (int m = 0; m < 4; m++)
        #pragma unroll
        for (int n = 0; n < 4; n++)
            acc[m][n] = f32x4{0.f, 0.f, 0.f, 0.f};

    for (int k0 = 0; k0 < DMODEL; k0 += 32) {
        __syncthreads();
        #pragma unroll
        for (int i = 0; i < 2; i++) {
            int e = (i * 256 + t) * 8;
            int r = e >> 5, c = e & 31;
            *reinterpret_cast<uint4*>(&Al[r * 40 + c]) =
                *reinterpret_cast<const uint4*>(&X[(size_t)(m0 + r) * DMODEL + k0 + c]);
            {
                const float* src = &W[(size_t)(n0 + r) * DMODEL + k0 + c];
                float4 v0 = *reinterpret_cast<const float4*>(src);
                float4 v1 = *reinterpret_cast<const float4*>(src + 4);
                f16x8 h = { (f16)v0.x, (f16)v0.y, (f16)v0.z, (f16)v0.w,
                            (f16)v1.x, (f16)v1.y, (f16)v1.z, (f16)v1.w };
                *reinterpret_cast<f16x8*>(&Bl[r * 40 + c]) = h;
            }
        }
        __syncthreads();
        f16x8 a[4], b[4];
        #pragma unroll
        for (int m = 0; m < 4; m++)
            a[m] = *reinterpret_cast<const f16x8*>(&Al[(wr * 64 + m * 16 + (lane & 15)) * 40 + (lane >> 4) * 8]);
        #pragma unroll
        for (int n = 0; n < 4; n++)
            b[n] = *reinterpret_cast<const f16x8*>(&Bl[(wc * 64 + n * 16 + (lane & 15)) * 40 + (lane >> 4) * 8]);
        #pragma unroll
        for (int m = 0; m < 4; m++)
            #pragma unroll
            for (int n = 0; n < 4; n++)
                acc[m][n] = __builtin_amdgcn_mfma_f32_16x16x32_f16(a[m], b[n], acc[m][n], 0, 0, 0);
    }

    const int rowb = m0 + wr * 64, colb = n0 + wc * 64;
    #pragma unroll
    for (int n = 0; n < 4; n++) {
        int cN = colb + n * 16 + (lane & 15);
        float bvv = bias[cN];
        #pragma unroll
        for (int m = 0; m < 4; m++) {
            #pragma unroll
            for (int rg = 0; rg < 4; rg++) {
                int r = rowb + m * 16 + (lane >> 4) * 4 + rg;
                out[(size_t)r * DMODEL + cN] = acc[m][n][rg] + bvv;
            }
        }
    }
}

// ---------------- flash attention: deferred-PV pipeline (unchanged) ----------------
__global__ __launch_bounds__(512) void attn_fwd(
    const f16* __restrict__ qb, const f16* __restrict__ kb,
    const f16* __restrict__ vt, f16* __restrict__ ctx)
{
    __shared__ f16 Kl[2][64 * 64];
    __shared__ f16 Vl[3][64 * 64];
    __shared__ f16 Pl[2][8 * 16 * LD];

    const int t = threadIdx.x, lane = t & 63, wid = t >> 6;
    const int q15 = lane & 15, g = lane >> 4;
    const int sw = q15 & 7;                 // read-side XOR key
    const int bh = blockIdx.y;
    const int q0 = blockIdx.x * 128 + wid * 16;

    const f16* qptr = qb + ((size_t)bh * S_LEN + q0) * HD;
    f16x8 qf0 = *reinterpret_cast<const f16x8*>(&qptr[q15 * HD + g * 8]);
    f16x8 qf1 = *reinterpret_cast<const f16x8*>(&qptr[q15 * HD + g * 8 + 32]);

    f32x4 ctxa[4];
    #pragma unroll
    for (int i = 0; i < 4; i++) ctxa[i] = f32x4{0.f, 0.f, 0.f, 0.f};
    float mrun = -3.0e38f, lrun = 0.f;

    const int srow = t >> 3;
    const int sslot = (t & 7) ^ (srow & 7);
    const f16* kg = kb + (size_t)bh * S_LEN * HD + (size_t)srow * HD + sslot * 8;
    const f16* vg = vt + (size_t)bh * HD * S_LEN + (size_t)srow * S_LEN + sslot * 8;
    const int lds_wbase = wid * 512;
    const int poff = wid * (16 * LD);

    gload16(kg, &Kl[0][lds_wbase]);
    gload16(vg, &Vl[0][lds_wbase]);
    __syncthreads();

    int kbuf = 0;
    int vprev = 2, vcur = 0, vnext = 1;

    for (int kt = 0; kt < NT; kt++) {
        if (kt + 1 < NT) {
            gload16(kg + (size_t)(kt + 1) * 64 * HD, &Kl[kbuf ^ 1][lds_wbase]);
            gload16(vg + (size_t)(kt + 1) * 64,      &Vl[vnext][lds_wbase]);
        }
        const f16* Kc = Kl[kbuf];

        f32x4 sc[4];
        __builtin_amdgcn_s_setprio(1);
        #pragma unroll
        for (int f = 0; f < 4; f++) {
            f16x8 kf0 = *reinterpret_cast<const f16x8*>(&Kc[(f * 16 + q15) * 64 + ((g ^ sw) * 8)]);
            f16x8 kf1 = *reinterpret_cast<const f16x8*>(&Kc[(f * 16 + q15) * 64 + (((g + 4) ^ sw) * 8)]);
            f32x4 z = {0.f, 0.f, 0.f, 0.f};
            z = __builtin_amdgcn_mfma_f32_16x16x32_f16(kf0, qf0, z, 0, 0, 0);
            sc[f] = __builtin_amdgcn_mfma_f32_16x16x32_f16(kf1, qf1, z, 0, 0, 0);
        }
        if (kt > 0) {
            const f16* Vp = Vl[vprev];
            const f16* pr = &Pl[(kt & 1) ^ 1][poff];
            #pragma unroll
            for (int c = 0; c < 2; c++) {
                f16x8 pfr = *reinterpret_cast<const f16x8*>(&pr[q15 * LD + g * 8 + c * 32]);
                #pragma unroll
                for (int n = 0; n < 4; n++) {
                    f16x8 vf = *reinterpret_cast<const f16x8*>(&Vp[(n * 16 + q15) * 64 + (((g + c * 4) ^ sw) * 8)]);
                    ctxa[n] = __builtin_amdgcn_mfma_f32_16x16x32_f16(vf, pfr, ctxa[n], 0, 0, 0);
                }
            }
        }
        __builtin_amdgcn_s_setprio(0);

        float pmf[4];
        #pragma unroll
        for (int f = 0; f < 4; f++)
            pmf[f] = fmaxf(fmaxf(sc[f][0], sc[f][1]), fmaxf(sc[f][2], sc[f][3]));
        float pm = fmaxf(fmaxf(pmf[0], pmf[1]), fmaxf(pmf[2], pmf[3]));
        if (!__all(pm - mrun <= 8.0f)) {
            float pmax = fmaxf(pm, __shfl_xor(pm, 16));
            pmax = fmaxf(pmax, __shfl_xor(pmax, 32));
            float mnew = fmaxf(mrun, pmax);
            float scale = __builtin_amdgcn_exp2f(mrun - mnew);
            lrun *= scale;
            #pragma unroll
            for (int n = 0; n < 4; n++) {
                ctxa[n][0] *= scale; ctxa[n][1] *= scale;
                ctxa[n][2] *= scale; ctxa[n][3] *= scale;
            }
            mrun = mnew;
        }
        float tsum = 0.f;
        #pragma unroll
        for (int f = 0; f < 4; f++)
            #pragma unroll
            for (int rg = 0; rg < 4; rg++) {
                float p = __builtin_amdgcn_exp2f(sc[f][rg] - mrun);
                sc[f][rg] = p;
                tsum += p;
            }
        lrun += tsum;

        f16* pw = &Pl[kt & 1][poff];
        #pragma unroll
        for (int f = 0; f < 4; f++) {
            f16x4 pwv = { (f16)sc[f][0], (f16)sc[f][1], (f16)sc[f][2], (f16)sc[f][3] };
            *reinterpret_cast<f16x4*>(&pw[q15 * LD + f * 16 + g * 4]) = pwv;
        }

        __syncthreads();
        kbuf ^= 1;
        int tmp = vprev; vprev = vcur; vcur = vnext; vnext = tmp;
    }

    // epilogue: PV(NT-1)
    {
        const f16* Vp = Vl[vprev];
        const f16* pr = &Pl[(NT - 1) & 1][poff];
        #pragma unroll
        for (int c = 0; c < 2; c++) {
            f16x8 pfr = *reinterpret_cast<const f16x8*>(&pr[q15 * LD + g * 8 + c * 32]);
            #pragma unroll
            for (int n = 0; n < 4; n++) {
                f16x8 vf = *reinterpret_cast<const f16x8*>(&Vp[(n * 16 + q15) * 64 + (((g + c * 4) ^ sw) * 8)]);
                ctxa[n] = __builtin_amdgcn_mfma_f32_16x16x32_f16(vf, pfr, ctxa[n], 0, 0, 0);
            }
        }
    }

    lrun += __shfl_xor(lrun, 16);
    lrun += __shfl_xor(lrun, 32);
    const int bi = bh >> 4, h = bh & 15;
    const int s = q0 + q15;
    float inv = 1.0f / lrun;
    f16* outp = &ctx[((size_t)s * BATCH + bi) * DMODEL + h * HD];
    #pragma unroll
    for (int n = 0; n < 4; n++) {
        f16x4 o = { (f16)(ctxa[n][0] * inv), (f16)(ctxa[n][1] * inv),
                    (f16)(ctxa[n][2] * inv), (f16)(ctxa[n][3] * inv) };
        *reinterpret_cast<f16x4*>(&outp[n * 16 + g * 4]) = o;
    }
}

// ---------------- launch ----------------
extern "C" void kernel_launch(void* const* d_in, const int* in_sizes, int n_in,
                              void* d_out, int out_size, void* d_ws, size_t ws_size,
                              hipStream_t stream)
{
    const float* Q  = (const float*)d_in[0];
    const float* K  = (const float*)d_in[1];
    const float* V  = (const float*)d_in[2];
    const float* Wq = (const float*)d_in[3];
    const float* bq = (const float*)d_in[4];
    const float* Wk = (const float*)d_in[5];
    const float* bk = (const float*)d_in[6];
    const float* Wv = (const float*)d_in[7];
    const float* bv = (const float*)d_in[8];
    const float* Wo = (const float*)d_in[9];
    const float* bo = (const float*)d_in[10];
    float* out = (float*)d_out;

    char* w = (char*)d_ws;
    const size_t MBc = 1024 * 1024;
    const size_t NEED_FAST = 40 * MBc + 256 * 1024;   // 40.25 MiB

    if (ws_size >= NEED_FAST) {
        // FAST layout:
        //   [0,8M)       f16 weights: Wq,Wk,Wv,Wo (2M ea)
        //   [8M,8.25M)   rc, rs
        //   [8.25M,40.25M) qbuf, kbuf, vtb, ctxb (8M ea)
        f16* Wqh = (f16*)w;
        f16* Wkh = Wqh + 1048576;
        f16* Wvh = Wqh + 2097152;
        f16* Woh = Wqh + 3145728;
        float* rc = (float*)(w + 8 * MBc);
        float* rs = rc + 32768;
        f16* qbuf = (f16*)(w + 8 * MBc + 256 * 1024);
        f16* kbuf = qbuf + 4194304;
        f16* vtb  = kbuf + 4194304;
        f16* ctxb = vtb + 4194304;

        rope_table<<<(S_LEN * 16) / 256, 256, 0, stream>>>(rc, rs);
        cvt_w<<<dim3(512, 4), 256, 0, stream>>>(Wq, Wk, Wv, Wo, Wqh);
        proj_gemm_h<<<dim3(MROWS / 128, DMODEL / 128, 3), 256, 0, stream>>>(
            Q, K, V, Wqh, Wkh, Wvh, bq, bk, bv, qbuf, kbuf, vtb, rc, rs);
        attn_fwd<<<dim3(S_LEN / 128, BATCH * NHEADS), 512, 0, stream>>>(qbuf, kbuf, vtb, ctxb);
        out_gemm_h<<<dim3(MROWS / 128, DMODEL / 128), 256, 0, stream>>>(ctxb, Woh, bo, out);
    } else {
        const size_t szT = (size_t)S_LEN * 16 * sizeof(float);
        const size_t szQ = (size_t)MROWS * DMODEL * sizeof(f16);
        float* rc  = (float*)(w);
        float* rs  = (float*)(w + szT);
        f16* qbuf = (f16*)(w + 2 * szT);
        f16* kbuf = (f16*)(w + 2 * szT + szQ);
        f16* vtb  = (f16*)(w + 2 * szT + 2 * szQ);
        f16* ctxb = (f16*)(w + 2 * szT + 3 * szQ);

        rope_table<<<(S_LEN * 16) / 256, 256, 0, stream>>>(rc, rs);
        proj_gemm<<<dim3(MROWS / 128, DMODEL / 128, 3), 256, 0, stream>>>(
            Q, K, V, Wq, Wk, Wv, bq, bk, bv, qbuf, kbuf, vtb, rc, rs);
        attn_fwd<<<dim3(S_LEN / 128, BATCH * NHEADS), 512, 0, stream>>>(qbuf, kbuf, vtb, ctxb);
        out_gemm<<<dim3(MROWS / 128, DMODEL / 128), 256, 0, stream>>>(ctxb, Wo, bo, out);
    }
}